// Round 3
// baseline (17.745 us; speedup 1.0000x reference)
//
#include <hip/hip_runtime.h>

// out[n,d,oc,r] = logsumexp_ic( x[n,0,d,ic,r] + w[d,ic,oc,r] )
//              = log( sum_ic exp(x) * exp(w) )   (no max-shift: |x+w| <~ 12)
//
// N=256, D=64, IC=32, OC=32, R=8. fp32 in/out.
// Block = one d x 64 n, 256 threads, grid = 64x4 = 256 blocks = 1/CU.
// Pipelined: stage w + x[0:32); prefetch x[32:64) into regs (T14) before the
// barrier; compute chunk0 while the prefetch flies; store chunk0 early so the
// writes drain under chunk1 compute. Thread tile = 8n x 4oc x 1r, all-b128 LDS.

constexpr int kD = 64, kIC = 32, kOC = 32, kR = 8;
constexpr int kNT = 64;                 // n rows per block (2 chunks of 32)
constexpr int PAD = 36, PQ = PAD / 4;   // 32 data + 4 pad floats per LDS row
constexpr int WS_FLOATS = kIC * kR * PAD;   // 9216  (36 KiB)
constexpr int XS_FLOATS = kNT * kR * PAD;   // 18432 (72 KiB)
constexpr size_t LDS_BYTES = (size_t)(WS_FLOATS + XS_FLOATS) * 4;  // 108 KiB

__device__ __forceinline__ void compute_store_chunk(
    const float* __restrict__ xs, const float* __restrict__ ws,
    float* __restrict__ out, int t, int d, int n0, int cbase)
{
    const int rr  = t & 7;
    const int och = (t >> 3) & 7;       // owns oc = k*8 + och, k=0..3
    const int ng  = t >> 6;             // wave id; wave = full (rr x och)
    const int nbase = cbase + ng * 8;   // 8 n rows per thread

    float acc[8][4];
    #pragma unroll
    for (int jj = 0; jj < 8; ++jj)
        #pragma unroll
        for (int k = 0; k < 4; ++k) acc[jj][k] = 0.f;

    const float4* xs4 = reinterpret_cast<const float4*>(xs);
    const float4* ws4 = reinterpret_cast<const float4*>(ws);

    #pragma unroll
    for (int icq = 0; icq < 8; ++icq) {
        float4 xq[8];
        #pragma unroll
        for (int jj = 0; jj < 8; ++jj)
            xq[jj] = xs4[((nbase + jj) * kR + rr) * PQ + icq];
        #pragma unroll
        for (int q = 0; q < 4; ++q) {
            const float4 wq = ws4[((icq * 4 + q) * kR + rr) * PQ + och];
            #pragma unroll
            for (int jj = 0; jj < 8; ++jj) {
                const float xqq = reinterpret_cast<const float*>(&xq[jj])[q];
                acc[jj][0] = fmaf(xqq, wq.x, acc[jj][0]);
                acc[jj][1] = fmaf(xqq, wq.y, acc[jj][1]);
                acc[jj][2] = fmaf(xqq, wq.z, acc[jj][2]);
                acc[jj][3] = fmaf(xqq, wq.w, acc[jj][3]);
            }
        }
    }

    // store: offset (k*8+och)*8 + rr = k*64 + och*8 + rr
    // per (jj,k) instr the wave's 64 lanes (rr x och) cover 256B contiguous
    #pragma unroll
    for (int jj = 0; jj < 8; ++jj) {
        const int n = n0 + nbase + jj;
        float* op = out + (size_t)n * (kD * kOC * kR) + (size_t)d * (kOC * kR)
                    + och * 8 + rr;
        #pragma unroll
        for (int k = 0; k < 4; ++k)
            op[k * 64] = __logf(acc[jj][k]);
    }
}

__global__ __launch_bounds__(256, 1) void lse_kernel(
    const float* __restrict__ x, const float* __restrict__ w,
    float* __restrict__ out)
{
    extern __shared__ float lds[];
    float* ws = lds;                    // [ic*8+r][36], oc at j=(oc&7)*4+(oc>>3)
    float* xs = lds + WS_FLOATS;        // [(nl*8+r)][36], col = ic

    const int t  = threadIdx.x;
    const int d  = blockIdx.x;
    const int n0 = blockIdx.y * kNT;

    // ---- issue w loads (1 KiB contiguous per wave per i)
    const float4* wg = reinterpret_cast<const float4*>(w + (size_t)d * (kIC * kOC * kR));
    float4 wv[8];
    #pragma unroll
    for (int i = 0; i < 8; ++i) wv[i] = wg[i * 256 + t];

    // ---- issue x chunk0 loads
    float4 x0v[8];
    #pragma unroll
    for (int i = 0; i < 8; ++i) {
        const int fidx = i * 256 + t;
        const int nl = fidx >> 6;            // 0..31
        const int e  = fidx & 63;
        x0v[i] = reinterpret_cast<const float4*>(
            x + (size_t)(n0 + nl) * (kD * kIC * kR) + (size_t)d * (kIC * kR))[e];
    }

    // ---- exp + write w: global [ic][oc][r] -> ws rows (ic*8+r)
    #pragma unroll
    for (int i = 0; i < 8; ++i) {
        const int lin = (i * 256 + t) * 4;
        const int ic = lin >> 8;
        const int oc = (lin >> 3) & 31;
        const int r0 = lin & 7;              // 0 or 4; comps cover r0..r0+3
        const int j  = (oc & 7) * 4 + (oc >> 3);
        float* p = &ws[(ic * kR + r0) * PAD + j];
        p[0 * PAD] = __expf(wv[i].x);
        p[1 * PAD] = __expf(wv[i].y);
        p[2 * PAD] = __expf(wv[i].z);
        p[3 * PAD] = __expf(wv[i].w);
    }

    // ---- exp + write x chunk0
    #pragma unroll
    for (int i = 0; i < 8; ++i) {
        const int fidx = i * 256 + t;
        const int nl = fidx >> 6;
        const int e  = fidx & 63;
        const int ic = e >> 1;
        const int r0 = (e & 1) * 4;
        float* p = &xs[(nl * kR + r0) * PAD + ic];
        p[0 * PAD] = __expf(x0v[i].x);
        p[1 * PAD] = __expf(x0v[i].y);
        p[2 * PAD] = __expf(x0v[i].z);
        p[3 * PAD] = __expf(x0v[i].w);
    }

    // ---- T14: issue x chunk1 loads NOW; consume after chunk0 compute
    float4 x1v[8];
    #pragma unroll
    for (int i = 0; i < 8; ++i) {
        const int fidx = i * 256 + t;
        const int nl = fidx >> 6;
        const int e  = fidx & 63;
        x1v[i] = reinterpret_cast<const float4*>(
            x + (size_t)(n0 + 32 + nl) * (kD * kIC * kR) + (size_t)d * (kIC * kR))[e];
    }

    __syncthreads();

    // ---- chunk0 compute + early stores (stores drain under chunk1)
    compute_store_chunk(xs, ws, out, t, d, n0, 0);

    // ---- exp + write x chunk1 (disjoint xs region; visible after barrier)
    #pragma unroll
    for (int i = 0; i < 8; ++i) {
        const int fidx = i * 256 + t;
        const int nl = fidx >> 6;
        const int e  = fidx & 63;
        const int ic = e >> 1;
        const int r0 = (e & 1) * 4;
        float* p = &xs[((32 + nl) * kR + r0) * PAD + ic];
        p[0 * PAD] = __expf(x1v[i].x);
        p[1 * PAD] = __expf(x1v[i].y);
        p[2 * PAD] = __expf(x1v[i].z);
        p[3 * PAD] = __expf(x1v[i].w);
    }

    __syncthreads();

    // ---- chunk1 compute + stores
    compute_store_chunk(xs, ws, out, t, d, n0, 32);
}

extern "C" void kernel_launch(void* const* d_in, const int* in_sizes, int n_in,
                              void* d_out, int out_size, void* d_ws, size_t ws_size,
                              hipStream_t stream) {
    const float* x = (const float*)d_in[0];
    const float* w = (const float*)d_in[1];
    float* out = (float*)d_out;
    // dynamic LDS > 64 KiB needs the attribute; idempotent + capture-safe
    (void)hipFuncSetAttribute((const void*)lse_kernel,
                              hipFuncAttributeMaxDynamicSharedMemorySize,
                              (int)LDS_BYTES);
    dim3 grid(kD, 256 / kNT);
    lse_kernel<<<grid, 256, LDS_BYTES, stream>>>(x, w, out);
}